// Round 17
// baseline (125.140 us; speedup 1.0000x reference)
//
#include <hip/hip_runtime.h>
#include <math.h>

#define NNT 48
#define LL 32
#define BB 32
#define N2 2304            // 48*48
#define KSTEPS 72          // 2304/32
#define EPSV 1e-30f
#define CH_J ((LL+1)*NNT)  // 1584
#define SEB_S 2328         // shorts per sEb row (2304 + pad)
#define PD_RS 20           // pD row stride (floats)
#define PD_T  328          // pD nt-tile stride (floats)
#define PD_W  984          // pD wave stride (floats)
#define NCELL (BB*LL*(LL+1)*NNT)   // 1,622,016 chart cells

typedef __attribute__((ext_vector_type(8))) short bf16x8;
typedef __attribute__((ext_vector_type(4))) float f32x4;
typedef __attribute__((ext_vector_type(4))) int   i32x4;

__device__ __forceinline__ int ch_idx(int b, int i, int j, int n) {
    return (((b*LL + i)*(LL+1) + j)*NNT + n);
}
__device__ __forceinline__ unsigned short f2bf(float x) {
    unsigned u = __float_as_uint(x);
    u = (u + 0x7fffu + ((u >> 16) & 1u)) >> 16;   // RNE
    return (unsigned short)u;
}
// packed f32x2 -> bf16x2 (RTZ) — one instruction (T12 primitive)
__device__ __forceinline__ int cvtpk(float lo, float hi) {
    int r;
    asm("v_cvt_pk_bf16_f32 %0, %1, %2" : "=v"(r) : "v"(lo), "v"(hi));
    return r;
}
// EU/EV slab addressing (shorts): [q][r=0..47][k=0..31] bf16, 16B-chunk XOR swizzle
__device__ __forceinline__ int uvt_base(int q, int r, int kc) {
    return q*1536 + ((((r << 2) + kc) ^ (r & 7)) << 3);
}
__device__ __forceinline__ float wavemax(float x) {
    #pragma unroll
    for (int o = 32; o; o >>= 1) x = fmaxf(x, __shfl_xor(x, o));
    return x;
}
// cross-XCD-safe (LLC-coherent) chart access — RELAXED, no inv/wb
__device__ __forceinline__ float ch_ld(const float* p) {
    return __hip_atomic_load(p, __ATOMIC_RELAXED, __HIP_MEMORY_SCOPE_AGENT);
}
__device__ __forceinline__ void ch_st(float* p, float v) {
    __hip_atomic_store(p, v, __ATOMIC_RELAXED, __HIP_MEMORY_SCOPE_AGENT);
}
// lgkm-only barrier: LDS ordering without draining in-flight chart stores
#define LBAR() { asm volatile("s_waitcnt lgkmcnt(0)" ::: "memory"); \
                 __builtin_amdgcn_s_barrier(); }

// prep: [0,432) pack W into MFMA B-frag order; [432,688) leaf rows + leaf rmax;
// [688,...) -inf sentinels into every non-leaf chart cell (data-as-flag).
__global__ void prep_kernel(const float* __restrict__ binary, const int* __restrict__ tokens,
                            const float* __restrict__ lexical, unsigned short* __restrict__ Wp,
                            float* __restrict__ chart, int T) {
    if (blockIdx.x < 432) {
        int idx = blockIdx.x*256 + threadIdx.x;       // 432*256 == 3*72*512
        int j  = idx & 7;
        int l  = (idx >> 3) & 63;
        int ks = (idx >> 9) % KSTEPS;
        int nt = idx / (KSTEPS*512);
        int e = ks*32 + ((l >> 4) << 3) + j;
        int n = nt*16 + (l & 15);
        int bp = e % 48, c = e / 48;
        Wp[idx] = f2bf(fmaxf(binary[n*N2 + bp*48 + c], EPSV));
    } else if (blockIdx.x < 688) {
        int row = (blockIdx.x - 432)*4 + (threadIdx.x >> 6);   // 1024 rows
        int lane = threadIdx.x & 63;
        int b = row >> 5, i = row & 31;
        int tok = tokens[b*LL + i];
        float val = (lane < NNT)
            ? __logf(fmaxf(lexical[(size_t)lane*(size_t)T + (size_t)tok], EPSV))
            : -INFINITY;
        float rm = wavemax(val);
        if (lane < NNT) chart[ch_idx(b, i, i+1, lane)] = val;
        if (lane == 0) chart[ch_idx(b, i, 0, i+1)] = rm;   // leaf rmax
    } else {
        int idx = (blockIdx.x - 688)*256 + threadIdx.x;
        if (idx < NCELL) {
            int n = idx % NNT;
            int r = idx / NNT;
            int j = r % (LL + 1);
            int i = (r / (LL + 1)) % LL;
            if (j != i + 1 && !(j == 0 && n == i + 1))
                chart[idx] = -INFINITY;
        }
    }
}

#define MFMA16(A,B,C) __builtin_amdgcn_mfma_f32_16x16x32_bf16(A,B,C,0,0,0)

// right-child row loads for split-slots [C*8, C*8+8) (kk = rr + t*2), clamped
#define LDVP(V, C, TCX, VPX)                                                   \
    { _Pragma("unroll")                                                        \
      for (int dt = 0; dt < 8; ++dt) {                                         \
          int t = (C)*8 + dt; int tt = (t < (TCX)) ? t : (TCX) - 1;            \
          int kk = rr + tt*2;                                                  \
          V[dt] = ch_ld((VPX) + kk*CH_J + ln);                                 \
      } }
// consume EV chunk: two-sided shift (old-split args <= 0), cvt_pk pack, b128
// slab write. zfix zeroes the fresh slot kk=0 (handled by the rank-1 path).
#define CONSCH(V, C)                                                           \
    { int pv[4];                                                               \
      _Pragma("unroll")                                                        \
      for (int dp = 0; dp < 4; ++dp) {                                         \
          int t0 = (C)*8 + 2*dp;                                               \
          int tt0 = (t0     < tc) ? t0     : tc - 1;                           \
          int tt1 = (t0 + 1 < tc) ? t0 + 1 : tc - 1;                           \
          float a0 = sRm[q][rr + tt0*2 + 1];                                   \
          float a1 = sRm[q][rr + tt1*2 + 1];                                   \
          float e0 = __expf(V[2*dp]     + a0 - M);                             \
          float e1 = __expf(V[2*dp + 1] + a1 - M);                             \
          if ((C) == 0 && dp == 0 && zfix) e0 = 0.f;                           \
          pv[dp] = cvtpk(e0, e1);                                              \
      }                                                                        \
      if (lane < NNT) {                                                        \
          int ad = uvt_base(w, lane, (C));                                     \
          *(i32x4*)&sUV[ad + 12288] = (i32x4){pv[0],pv[1],pv[2],pv[3]};        \
      } }

// 256 blocks, 512 thr. Gang of 8 blocks per b at blockIdx = b + 32c (same XCD).
// Block c owns i = 28-4c..31-4c; 2 waves per instance (split parity).
// Level-invariant: Wp in 108 VGPRs; EU slabs persistent (new slot written in
// the epilogue from val/rm); eu0 (leaf exp) held in a register.
// DEFER-MAX (s>2): shift M' = max over kk>=1 only (all data old ->
// zero-wait); main 9 MFMAs run with the fresh EV slot zeroed; the fresh
// split kk=0 is folded afterwards as a register-only rank-1 MFMA update
// (one-hot K frags via shuffles). beta_0 is never needed. The fresh v-row
// comes from LDS (q<3) or an early-issued LLC load (q=3) whose latency
// hides under stage-1's work.
__global__ __launch_bounds__(512, 2) void inside_kernel(
        const unsigned short* __restrict__ Wp,
        float* __restrict__ chart,
        float* __restrict__ out) {
    const int pb = blockIdx.x;
    const int b = pb & 31, c = pb >> 5;
    const int i_base = 28 - 4*c;
    const int tid = threadIdx.x, lane = tid & 63, w = tid >> 6;
    const int fr = lane & 15, kg = lane >> 4;
    const int ln = (lane < NNT) ? lane : 0;
    const int q = w >> 1, rr = w & 1;       // instance slot, split parity
    const int i0 = i_base + q;

    __shared__ __align__(16) short sUV[24576];       // EU(persist) | EV(+12288)
    __shared__ __align__(16) short sEb[16*SEB_S];    //                 74.5 KB
    __shared__ float pD[8*PD_W];                     //                 31.5 KB
    __shared__ float sRm[4][33];                     // own-row maxima cache
    __shared__ float sOut[4][NNT];                   // own prev-level outputs

    for (int x = tid; x < 12288; x += 512) ((int*)sUV)[x] = 0;
    for (int x = tid; x < 18624; x += 512) ((int*)sEb)[x] = 0;
    if (tid < 4)   // own leaf rmax -> cache
        sRm[tid][1] = ch_ld(&chart[ch_idx(b, i_base + tid, 0, i_base + tid + 1)]);
    if (w < 4 && lane < NNT)   // own leaf rows (v0 source at s=2; eu0 seed)
        sOut[w][lane] = ch_ld(&chart[ch_idx(b, i_base + w, i_base + w + 1, lane)]);

    // level-invariant Wp B-fragments -> 108 VGPRs (stage-2 is VMEM-free)
    const bf16x8* wp8 = (const bf16x8*)Wp;
    const int kstart = 9*w;
    bf16x8 wreg[9][3];
    #pragma unroll
    for (int t = 0; t < 9; ++t)
        #pragma unroll
        for (int nt = 0; nt < 3; ++nt)
            wreg[t][nt] = wp8[(nt*KSTEPS + kstart + t)*64 + lane];

    // ---- cross-level prefetch registers + prologue (level 2: all leaves)
    float vvP0[8] = {0,0,0,0,0,0,0,0}, vvP1[8] = {0,0,0,0,0,0,0,0}, btP = 0.f;
    if (i0 <= LL - 2) {
        const int nkn = 1, tcn = (nkn - rr + 1) >> 1;
        if (tcn > 0) {
            const float* vpn = chart + ch_idx(b, i0 + 1, i0 + 2, 0);
            const float* bpn = chart + ch_idx(b, i0 + 1, 0, i0 + 2);
            btP = (lane < nkn) ? ch_ld(bpn + lane*CH_J) : 0.f;
            LDVP(vvP0, 0, tcn, vpn)
        }
    }

    __syncthreads();

    // eu0: fresh split's LEFT factor = leaf row -> level-invariant register
    float eu0reg = (lane < NNT) ? __expf(sOut[q][lane] - sRm[q][1]) : 0.f;
    // seed EU slab slot kk=0 (owned by wave parity 0)
    if (rr == 0 && lane < NNT)
        sUV[uvt_base(w, lane, 0)] = (short)f2bf(eu0reg);

    for (int s = 2; s <= LL; ++s) {
        const int nk = s - 1;
        if (i_base > LL - s) return;                       // block done forever

        const bool active = (i0 <= LL - s);
        const int tc = active ? ((nk - rr + 1) >> 1) : 0;  // owned splits (parity rr)
        const bool defer = (s > 2);
        const int zfix = (defer && rr == 0) ? 1 : 0;
        float M = -INFINITY;
        f32x4 ea[9];
        #pragma unroll
        for (int z = 0; z < 9; ++z) ea[z] = (f32x4){0.f, 0.f, 0.f, 0.f};

        if (tc > 0) {
            const float* vp = chart + ch_idx(b, i0 + 1, i0 + s, 0);
            const float* bp = chart + ch_idx(b, i0 + 1, 0, i0 + s);  // beta col

            // early fresh-row load for the cross-block boundary wave
            float vfresh = 0.f;
            if (defer && q == 3 && rr == 0) vfresh = ch_ld(vp + ln);

            // spin on provably-old values only (fresh slot excluded for defer)
            for (;;) {
                bool bad;
                if (defer) {
                    bad = (lane >= 1 && lane < nk) && (btP == -INFINITY);
                    #pragma unroll
                    for (int dt = 0; dt < 8; ++dt)
                        if (!(rr == 0 && dt == 0)) bad |= (vvP0[dt] == -INFINITY);
                } else {
                    bad = (lane < nk) && (btP == -INFINITY);
                    #pragma unroll
                    for (int dt = 0; dt < 8; ++dt) bad |= (vvP0[dt] == -INFINITY);
                }
                if (tc > 8) {
                    #pragma unroll
                    for (int dt = 0; dt < 8; ++dt) bad |= (vvP1[dt] == -INFINITY);
                }
                if (!__any(bad)) break;
                btP = (lane < nk) ? ch_ld(bp + lane*CH_J) : 0.f;
                LDVP(vvP0, 0, tc, vp)
                if (tc > 8) { LDVP(vvP1, 1, tc, vp) }
            }

            // shift M': defer -> max over OLD splits only; s==2 -> full max
            {
                float al = (lane < nk) ? sRm[q][lane + 1] : -INFINITY;
                bool use = defer ? (lane >= 1 && lane < nk) : (lane < nk);
                M = wavemax(use ? (al + btP) : -INFINITY);
            }

            CONSCH(vvP0, 0)
            if (tc > 8) { CONSCH(vvP1, 1) }

            // stage-1 MFMA (main): old splits (fresh EV slot is zero)
            bf16x8 A0 = *(const bf16x8*)&sUV[uvt_base(w,  0 + fr, kg)];
            bf16x8 A1 = *(const bf16x8*)&sUV[uvt_base(w, 16 + fr, kg)];
            bf16x8 A2 = *(const bf16x8*)&sUV[uvt_base(w, 32 + fr, kg)];
            bf16x8 B0 = *(const bf16x8*)&sUV[12288 + uvt_base(w,  0 + fr, kg)];
            bf16x8 B1 = *(const bf16x8*)&sUV[12288 + uvt_base(w, 16 + fr, kg)];
            bf16x8 B2 = *(const bf16x8*)&sUV[12288 + uvt_base(w, 32 + fr, kg)];
            ea[0] = MFMA16(A0,B0,ea[0]); ea[1] = MFMA16(A0,B1,ea[1]); ea[2] = MFMA16(A0,B2,ea[2]);
            ea[3] = MFMA16(A1,B0,ea[3]); ea[4] = MFMA16(A1,B1,ea[4]); ea[5] = MFMA16(A1,B2,ea[5]);
            ea[6] = MFMA16(A2,B0,ea[6]); ea[7] = MFMA16(A2,B1,ea[7]); ea[8] = MFMA16(A2,B2,ea[8]);

            // rank-1 fold of the fresh split kk=0 (rr==0 waves, s>2)
            if (defer && rr == 0) {
                float v0;
                if (q < 3) {
                    v0 = sOut[q + 1][ln];
                } else {
                    for (;;) {
                        if (!__any((lane < NNT) && (vfresh == -INFINITY))) break;
                        vfresh = ch_ld(vp + ln);
                    }
                    v0 = vfresh;
                }
                float a0s = sRm[q][1];
                float ev0 = (lane < NNT) ? __expf(fminf(v0 + a0s - M, 80.f)) : 0.f;
                float sA0 = __shfl(eu0reg, fr), sA1 = __shfl(eu0reg, 16 + fr),
                      sA2 = __shfl(eu0reg, 32 + fr);
                float sB0 = __shfl(ev0, fr), sB1 = __shfl(ev0, 16 + fr),
                      sB2 = __shfl(ev0, 32 + fr);
                bf16x8 z8 = {0,0,0,0,0,0,0,0};
                bf16x8 Ar0 = z8, Ar1 = z8, Ar2 = z8, Br0 = z8, Br1 = z8, Br2 = z8;
                if (kg == 0) {
                    Ar0[0] = (short)f2bf(sA0); Ar1[0] = (short)f2bf(sA1);
                    Ar2[0] = (short)f2bf(sA2);
                    Br0[0] = (short)f2bf(sB0); Br1[0] = (short)f2bf(sB1);
                    Br2[0] = (short)f2bf(sB2);
                }
                ea[0] = MFMA16(Ar0,Br0,ea[0]); ea[1] = MFMA16(Ar0,Br1,ea[1]); ea[2] = MFMA16(Ar0,Br2,ea[2]);
                ea[3] = MFMA16(Ar1,Br0,ea[3]); ea[4] = MFMA16(Ar1,Br1,ea[4]); ea[5] = MFMA16(Ar1,Br2,ea[5]);
                ea[6] = MFMA16(Ar2,Br0,ea[6]); ea[7] = MFMA16(Ar2,Br1,ea[7]); ea[8] = MFMA16(Ar2,Br2,ea[8]);
            }
        }

        // issue NEXT level's v/beta prefetch (kk>=1 values provably final)
        if (s < LL && i0 <= LL - s - 1) {
            const int nkn = s;
            const int tcn = (nkn - rr + 1) >> 1;
            const float* vpn = chart + ch_idx(b, i0 + 1, i0 + s + 1, 0);
            const float* bpn = chart + ch_idx(b, i0 + 1, 0, i0 + s + 1);
            btP = (lane < nkn) ? ch_ld(bpn + lane*CH_J) : 0.f;
            LDVP(vvP0, 0, tcn, vpn)
            if (tcn > 8) { LDVP(vvP1, 1, tcn, vpn) }
        }

        // pack partial E -> sEb row w (cvt_pk, RTZ)
        if (active) {
            #pragma unroll
            for (int mt = 0; mt < 3; ++mt) {
                #pragma unroll
                for (int ct = 0; ct < 3; ++ct) {
                    f32x4 d = ea[mt*3 + ct];
                    int e0 = (ct*16 + fr)*48 + mt*16 + kg*4;
                    unsigned lo = (unsigned)cvtpk(d[0], d[1]);
                    unsigned hi = (unsigned)cvtpk(d[2], d[3]);
                    *(unsigned long long*)&sEb[w*SEB_S + e0] =
                        (unsigned long long)lo | ((unsigned long long)hi << 32);
                }
            }
        }

        LBAR();   // B2: sEb visible (chart stores stay in flight)

        // stage-2: K-split MFMA GEMM [16 x 2304] x [2304 x 48] — VMEM-free
        {
            f32x4 c0 = {0.f,0.f,0.f,0.f}, c1 = c0, c2 = c0;
            #pragma unroll
            for (int t = 0; t < 9; ++t) {
                bf16x8 af = *(const bf16x8*)&sEb[fr*SEB_S + (kstart + t)*32 + kg*8];
                c0 = MFMA16(af, wreg[t][0], c0);
                c1 = MFMA16(af, wreg[t][1], c1);
                c2 = MFMA16(af, wreg[t][2], c2);
            }
            #pragma unroll
            for (int r2 = 0; r2 < 4; ++r2) {
                int row = kg*4 + r2;
                pD[w*PD_W + 0*PD_T + row*PD_RS + fr] = c0[r2];
                pD[w*PD_W + 1*PD_T + row*PD_RS + fr] = c1[r2];
                pD[w*PD_W + 2*PD_T + row*PD_RS + fr] = c2[r2];
            }
        }
        LBAR();   // B3: pD visible

        // epilogue: wave rr==0 of instance q -> publish row (chart + LDS)
        // + write next level's NEW EU slot directly from val/rm
        if (active && rr == 0) {
            float sum = 0.f;
            #pragma unroll
            for (int w2 = 0; w2 < 8; ++w2) {
                const float* pp = &pD[w2*PD_W + (ln >> 4)*PD_T + (ln & 15)];
                sum += pp[(2*q)*PD_RS] + pp[(2*q + 1)*PD_RS];
            }
            float val = M + __logf(sum);
            float rm = wavemax((lane < NNT) ? val : -INFINITY);
            if (lane < NNT) {
                ch_st(&chart[ch_idx(b, i0, i0 + s, lane)], val);
                sOut[q][lane] = val;
                // next level's new split kk = s-1 (parity (s-1)&1)
                int rrn = (s - 1) & 1;
                int tn  = (s - 1 - rrn) >> 1;
                sUV[uvt_base(2*q + rrn, lane, tn >> 3) + (tn & 7)] =
                    (short)f2bf(__expf(val - rm));
            }
            if (lane == 0) {
                ch_st(&chart[ch_idx(b, i0, 0, i0 + s)], rm);
                sRm[q][s] = rm;
                if (s == LL) out[b] = val;
            }
        }
        LBAR();   // B4: sOut/sRm/EU-slot visible; LDS reuse safe
    }
}

extern "C" void kernel_launch(void* const* d_in, const int* in_sizes, int n_in,
                              void* d_out, int out_size, void* d_ws, size_t ws_size,
                              hipStream_t stream) {
    const int*   tokens  = (const int*)d_in[0];
    const float* binary  = (const float*)d_in[1];
    const float* lexical = (const float*)d_in[2];
    float* out = (float*)d_out;

    float* chart = (float*)d_ws;                                   // 6.49 MB
    unsigned short* Wp = (unsigned short*)(chart + (size_t)NCELL); // 221 KB bf16

    int T = in_sizes[2] / NNT;   // 32000

    int fill_blocks = (NCELL + 255)/256;                           // 6336
    prep_kernel<<<688 + fill_blocks, 256, 0, stream>>>(binary, tokens, lexical, Wp, chart, T);
    inside_kernel<<<256, 512, 0, stream>>>(Wp, chart, out);
}

// Round 18
// 123.254 us; speedup vs baseline: 1.0153x; 1.0153x over previous
//
#include <hip/hip_runtime.h>
#include <math.h>

#define NNT 48
#define LL 32
#define BB 32
#define N2 2304            // 48*48
#define KSTEPS 72          // 2304/32
#define EPSV 1e-30f
#define CH_J ((LL+1)*NNT)  // 1584
#define SEB_S 2328         // shorts per sEb row (2304 + pad)
#define PD_RS 20           // pD row stride (floats)
#define PD_T  328          // pD nt-tile stride (floats)
#define PD_W  984          // pD wave stride (floats)
#define NCELL (BB*LL*(LL+1)*NNT)   // 1,622,016 chart cells

typedef __attribute__((ext_vector_type(8))) short bf16x8;
typedef __attribute__((ext_vector_type(4))) float f32x4;
typedef __attribute__((ext_vector_type(4))) int   i32x4;

__device__ __forceinline__ int ch_idx(int b, int i, int j, int n) {
    return (((b*LL + i)*(LL+1) + j)*NNT + n);
}
__device__ __forceinline__ unsigned short f2bf(float x) {
    unsigned u = __float_as_uint(x);
    u = (u + 0x7fffu + ((u >> 16) & 1u)) >> 16;   // RNE
    return (unsigned short)u;
}
// packed f32x2 -> bf16x2 (RTZ) — one instruction (T12 primitive)
__device__ __forceinline__ int cvtpk(float lo, float hi) {
    int r;
    asm("v_cvt_pk_bf16_f32 %0, %1, %2" : "=v"(r) : "v"(lo), "v"(hi));
    return r;
}
// EU/EV slab addressing (shorts): [q][r=0..47][k=0..31] bf16, 16B-chunk XOR swizzle
__device__ __forceinline__ int uvt_base(int q, int r, int kc) {
    return q*1536 + ((((r << 2) + kc) ^ (r & 7)) << 3);
}
__device__ __forceinline__ float wavemax(float x) {
    #pragma unroll
    for (int o = 32; o; o >>= 1) x = fmaxf(x, __shfl_xor(x, o));
    return x;
}
// cross-XCD-safe (LLC-coherent) chart access — RELAXED, no inv/wb
__device__ __forceinline__ float ch_ld(const float* p) {
    return __hip_atomic_load(p, __ATOMIC_RELAXED, __HIP_MEMORY_SCOPE_AGENT);
}
__device__ __forceinline__ void ch_st(float* p, float v) {
    __hip_atomic_store(p, v, __ATOMIC_RELAXED, __HIP_MEMORY_SCOPE_AGENT);
}
// lgkm-only barrier: LDS ordering without draining in-flight chart stores
#define LBAR() { asm volatile("s_waitcnt lgkmcnt(0)" ::: "memory"); \
                 __builtin_amdgcn_s_barrier(); }

// prep: [0,432) pack W into MFMA B-frag order; [432,688) leaf rows + leaf rmax;
// [688,...) -inf sentinels into every non-leaf chart cell (data-as-flag).
__global__ void prep_kernel(const float* __restrict__ binary, const int* __restrict__ tokens,
                            const float* __restrict__ lexical, unsigned short* __restrict__ Wp,
                            float* __restrict__ chart, int T) {
    if (blockIdx.x < 432) {
        int idx = blockIdx.x*256 + threadIdx.x;       // 432*256 == 3*72*512
        int j  = idx & 7;
        int l  = (idx >> 3) & 63;
        int ks = (idx >> 9) % KSTEPS;
        int nt = idx / (KSTEPS*512);
        int e = ks*32 + ((l >> 4) << 3) + j;
        int n = nt*16 + (l & 15);
        int bp = e % 48, c = e / 48;
        Wp[idx] = f2bf(fmaxf(binary[n*N2 + bp*48 + c], EPSV));
    } else if (blockIdx.x < 688) {
        int row = (blockIdx.x - 432)*4 + (threadIdx.x >> 6);   // 1024 rows
        int lane = threadIdx.x & 63;
        int b = row >> 5, i = row & 31;
        int tok = tokens[b*LL + i];
        float val = (lane < NNT)
            ? __logf(fmaxf(lexical[(size_t)lane*(size_t)T + (size_t)tok], EPSV))
            : -INFINITY;
        float rm = wavemax(val);
        if (lane < NNT) chart[ch_idx(b, i, i+1, lane)] = val;
        if (lane == 0) chart[ch_idx(b, i, 0, i+1)] = rm;   // leaf rmax
    } else {
        int idx = (blockIdx.x - 688)*256 + threadIdx.x;
        if (idx < NCELL) {
            int n = idx % NNT;
            int r = idx / NNT;
            int j = r % (LL + 1);
            int i = (r / (LL + 1)) % LL;
            if (j != i + 1 && !(j == 0 && n == i + 1))
                chart[idx] = -INFINITY;
        }
    }
}

#define MFMA16(A,B,C) __builtin_amdgcn_mfma_f32_16x16x32_bf16(A,B,C,0,0,0)

// right-child row loads for split-slots [C*8, C*8+8) (kk = rr + t*2), clamped
#define LDVP(V, C, TCX, VPX)                                                   \
    { _Pragma("unroll")                                                        \
      for (int dt = 0; dt < 8; ++dt) {                                         \
          int t = (C)*8 + dt; int tt = (t < (TCX)) ? t : (TCX) - 1;            \
          int kk = rr + tt*2;                                                  \
          V[dt] = ch_ld((VPX) + kk*CH_J + ln);                                 \
      } }
// consume EV chunk: two-sided shift (args <= 0), cvt_pk pack, b128 slab write
#define CONSCH(V, C)                                                           \
    { int pv[4];                                                               \
      _Pragma("unroll")                                                        \
      for (int dp = 0; dp < 4; ++dp) {                                         \
          int t0 = (C)*8 + 2*dp;                                               \
          int tt0 = (t0     < tc) ? t0     : tc - 1;                           \
          int tt1 = (t0 + 1 < tc) ? t0 + 1 : tc - 1;                           \
          float a0 = sRm[q][rr + tt0*2 + 1];                                   \
          float a1 = sRm[q][rr + tt1*2 + 1];                                   \
          float e0 = __expf(V[2*dp]     + a0 - M);                             \
          float e1 = __expf(V[2*dp + 1] + a1 - M);                             \
          pv[dp] = cvtpk(e0, e1);                                              \
      }                                                                        \
      if (lane < NNT) {                                                        \
          int ad = uvt_base(w, lane, (C));                                     \
          *(i32x4*)&sUV[ad + 12288] = (i32x4){pv[0],pv[1],pv[2],pv[3]};        \
      } }

// 256 blocks, 512 thr. Gang of 8 blocks per b at blockIdx = b + 32c (same XCD).
// Block c owns i = 28-4c..31-4c; 2 waves per instance (split parity).
// Level-invariant: Wp in 108 VGPRs (stage-2 VMEM-free); EU slabs persistent.
// REDUNDANT EPILOGUE: after B3, BOTH waves of instance q compute the epilogue
// of q AND of q+1 (shifts via sM[4], written in stage-1, visible after B2).
// The fresh v-row/beta for next level land in REGISTERS (v0Reg/rmN); each
// wave writes its OWN EU slab slot; sRm written by both waves (identical
// value -> race-benign). B4 is ELIMINATED (2 barriers/level).
// q=3's fresh dep stays a targeted cross-block LLC load.
__global__ __launch_bounds__(512, 2) void inside_kernel(
        const unsigned short* __restrict__ Wp,
        float* __restrict__ chart,
        float* __restrict__ out) {
    const int pb = blockIdx.x;
    const int b = pb & 31, c = pb >> 5;
    const int i_base = 28 - 4*c;
    const int tid = threadIdx.x, lane = tid & 63, w = tid >> 6;
    const int fr = lane & 15, kg = lane >> 4;
    const int ln = (lane < NNT) ? lane : 0;
    const int q = w >> 1, rr = w & 1;       // instance slot, split parity
    const int i0 = i_base + q;

    __shared__ __align__(16) short sUV[24576];       // EU(persist) | EV(+12288)
    __shared__ __align__(16) short sEb[16*SEB_S];    //                 74.5 KB
    __shared__ float pD[8*PD_W];                     //                 31.5 KB
    __shared__ float sRm[4][33];                     // own-row maxima cache
    __shared__ float sM[4];                          // per-instance shift

    for (int x = tid; x < 12288; x += 512) ((int*)sUV)[x] = 0;
    for (int x = tid; x < 18624; x += 512) ((int*)sEb)[x] = 0;
    if (tid < 4)   // own leaf rmax -> cache
        sRm[tid][1] = ch_ld(&chart[ch_idx(b, i_base + tid, 0, i_base + tid + 1)]);

    // level-invariant Wp B-fragments -> 108 VGPRs (stage-2 is VMEM-free)
    const bf16x8* wp8 = (const bf16x8*)Wp;
    const int kstart = 9*w;
    bf16x8 wreg[9][3];
    #pragma unroll
    for (int t = 0; t < 9; ++t)
        #pragma unroll
        for (int nt = 0; nt < 3; ++nt)
            wreg[t][nt] = wp8[(nt*KSTEPS + kstart + t)*64 + lane];

    // ---- cross-level prefetch registers + prologue (level 2: all leaves)
    float vvP0[8] = {0,0,0,0,0,0,0,0}, vvP1[8] = {0,0,0,0,0,0,0,0}, btP = 0.f;
    if (i0 <= LL - 2) {
        const int nkn = 1, tcn = (nkn - rr + 1) >> 1;
        if (tcn > 0) {
            const float* vpn = chart + ch_idx(b, i0 + 1, i0 + 2, 0);
            const float* bpn = chart + ch_idx(b, i0 + 1, 0, i0 + 2);
            btP = (lane < nkn) ? ch_ld(bpn + lane*CH_J) : 0.f;
            LDVP(vvP0, 0, tcn, vpn)
        }
    }

    __syncthreads();

    // seed EU slab slot kk=0 (parity 0) from own leaf row (own-wave write)
    {
        float lf = ch_ld(&chart[ch_idx(b, i0, i0 + 1, ln)]);
        float rmOwn = wavemax((lane < NNT) ? lf : -INFINITY);
        if (rr == 0 && lane < NNT)
            sUV[uvt_base(w, lane, 0)] = (short)f2bf(__expf(lf - rmOwn));
    }

    float v0Reg = 0.f, rmN = -INFINITY;   // fresh register path (q<3)

    for (int s = 2; s <= LL; ++s) {
        const int nk = s - 1;
        if (i_base > LL - s) return;                       // block done forever

        const bool active = (i0 <= LL - s);
        const int tc = active ? ((nk - rr + 1) >> 1) : 0;  // owned splits (parity rr)
        float M = -INFINITY;
        f32x4 ea[9];
        #pragma unroll
        for (int z = 0; z < 9; ++z) ea[z] = (f32x4){0.f, 0.f, 0.f, 0.f};

        if (tc > 0) {
            const float* vp = chart + ch_idx(b, i0 + 1, i0 + s, 0);
            const float* bp = chart + ch_idx(b, i0 + 1, 0, i0 + s);  // beta col

            // targeted cross-block fresh loads (boundary instance only)
            float vfresh = -INFINITY, b0fresh = -INFINITY;
            if (s > 2 && q == 3) {
                if (rr == 0) vfresh = ch_ld(vp + ln);
                b0fresh = ch_ld(bp);
            }

            // spin on provably-OLD prefetched values only
            for (;;) {
                bool bad;
                if (s > 2) {
                    bad = (lane >= 1 && lane < nk) && (btP == -INFINITY);
                    #pragma unroll
                    for (int dt = 0; dt < 8; ++dt)
                        if (!(rr == 0 && dt == 0)) bad |= (vvP0[dt] == -INFINITY);
                } else {
                    bad = (lane < nk) && (btP == -INFINITY);
                    #pragma unroll
                    for (int dt = 0; dt < 8; ++dt) bad |= (vvP0[dt] == -INFINITY);
                }
                if (tc > 8) {
                    #pragma unroll
                    for (int dt = 0; dt < 8; ++dt) bad |= (vvP1[dt] == -INFINITY);
                }
                if (!__any(bad)) break;
                btP = (lane < nk) ? ch_ld(bp + lane*CH_J) : 0.f;
                LDVP(vvP0, 0, tc, vp)
                if (tc > 8) { LDVP(vvP1, 1, tc, vp) }
            }
            // validate targeted fresh loads (q=3)
            if (s > 2 && q == 3) {
                for (;;) {
                    bool bad = ((rr == 0) && (lane < NNT) && (vfresh == -INFINITY))
                             || ((lane == 0) && (b0fresh == -INFINITY));
                    if (!__any(bad)) break;
                    if (rr == 0 && vfresh == -INFINITY) vfresh = ch_ld(vp + ln);
                    if (b0fresh == -INFINITY) b0fresh = ch_ld(bp);
                }
            }

            // M = max_k (alpha_k + beta_k); fresh beta0 from register/targeted
            {
                float btv = btP;
                if (s > 2 && lane == 0) btv = (q < 3) ? rmN : b0fresh;
                float al = (lane < nk) ? sRm[q][lane + 1] : -INFINITY;
                M = wavemax((lane < nk) ? al + btv : -INFINITY);
            }
            if (rr == 0 && lane == 0) sM[q] = M;   // visible to all after B2

            // patch fresh v-row (kk=0, owned by rr==0)
            if (s > 2 && rr == 0) vvP0[0] = (q < 3) ? v0Reg : vfresh;

            CONSCH(vvP0, 0)
            if (tc > 8) { CONSCH(vvP1, 1) }

            // stage-1 MFMA: E[b'][c] partial = sum_t EU[t][b'] * EV[t][c]
            bf16x8 A0 = *(const bf16x8*)&sUV[uvt_base(w,  0 + fr, kg)];
            bf16x8 A1 = *(const bf16x8*)&sUV[uvt_base(w, 16 + fr, kg)];
            bf16x8 A2 = *(const bf16x8*)&sUV[uvt_base(w, 32 + fr, kg)];
            bf16x8 B0 = *(const bf16x8*)&sUV[12288 + uvt_base(w,  0 + fr, kg)];
            bf16x8 B1 = *(const bf16x8*)&sUV[12288 + uvt_base(w, 16 + fr, kg)];
            bf16x8 B2 = *(const bf16x8*)&sUV[12288 + uvt_base(w, 32 + fr, kg)];
            ea[0] = MFMA16(A0,B0,ea[0]); ea[1] = MFMA16(A0,B1,ea[1]); ea[2] = MFMA16(A0,B2,ea[2]);
            ea[3] = MFMA16(A1,B0,ea[3]); ea[4] = MFMA16(A1,B1,ea[4]); ea[5] = MFMA16(A1,B2,ea[5]);
            ea[6] = MFMA16(A2,B0,ea[6]); ea[7] = MFMA16(A2,B1,ea[7]); ea[8] = MFMA16(A2,B2,ea[8]);
        }

        // issue NEXT level's v/beta prefetch (kk>=1 values provably final)
        if (s < LL && i0 <= LL - s - 1) {
            const int nkn = s;
            const int tcn = (nkn - rr + 1) >> 1;
            const float* vpn = chart + ch_idx(b, i0 + 1, i0 + s + 1, 0);
            const float* bpn = chart + ch_idx(b, i0 + 1, 0, i0 + s + 1);
            btP = (lane < nkn) ? ch_ld(bpn + lane*CH_J) : 0.f;
            LDVP(vvP0, 0, tcn, vpn)
            if (tcn > 8) { LDVP(vvP1, 1, tcn, vpn) }
        }

        // pack partial E -> sEb row w (cvt_pk, RTZ)
        if (active) {
            #pragma unroll
            for (int mt = 0; mt < 3; ++mt) {
                #pragma unroll
                for (int ct = 0; ct < 3; ++ct) {
                    f32x4 d = ea[mt*3 + ct];
                    int e0 = (ct*16 + fr)*48 + mt*16 + kg*4;
                    unsigned lo = (unsigned)cvtpk(d[0], d[1]);
                    unsigned hi = (unsigned)cvtpk(d[2], d[3]);
                    *(unsigned long long*)&sEb[w*SEB_S + e0] =
                        (unsigned long long)lo | ((unsigned long long)hi << 32);
                }
            }
        }

        LBAR();   // B2: sEb + sM visible (chart stores stay in flight)

        // stage-2: K-split MFMA GEMM [16 x 2304] x [2304 x 48] — VMEM-free
        {
            f32x4 c0 = {0.f,0.f,0.f,0.f}, c1 = c0, c2 = c0;
            #pragma unroll
            for (int t = 0; t < 9; ++t) {
                bf16x8 af = *(const bf16x8*)&sEb[fr*SEB_S + (kstart + t)*32 + kg*8];
                c0 = MFMA16(af, wreg[t][0], c0);
                c1 = MFMA16(af, wreg[t][1], c1);
                c2 = MFMA16(af, wreg[t][2], c2);
            }
            #pragma unroll
            for (int r2 = 0; r2 < 4; ++r2) {
                int row = kg*4 + r2;
                pD[w*PD_W + 0*PD_T + row*PD_RS + fr] = c0[r2];
                pD[w*PD_W + 1*PD_T + row*PD_RS + fr] = c1[r2];
                pD[w*PD_W + 2*PD_T + row*PD_RS + fr] = c2[r2];
            }
        }
        LBAR();   // B3: pD visible

        // ---- redundant epilogue: BOTH waves of instance q compute q (and q+1)
        if (active) {
            const float Mq = sM[q];
            float sum = 0.f;
            #pragma unroll
            for (int w2 = 0; w2 < 8; ++w2) {
                const float* pp = &pD[w2*PD_W + (ln >> 4)*PD_T + (ln & 15)];
                sum += pp[(2*q)*PD_RS] + pp[(2*q + 1)*PD_RS];
            }
            float val = Mq + __logf(sum);
            float rm = wavemax((lane < NNT) ? val : -INFINITY);
            if (rr == 0) {
                if (lane < NNT) ch_st(&chart[ch_idx(b, i0, i0 + s, lane)], val);
                if (lane == 0) {
                    ch_st(&chart[ch_idx(b, i0, 0, i0 + s)], rm);
                    if (s == LL) out[b] = val;
                }
            }
            if (lane == 0) sRm[q][s] = rm;   // both waves, identical value
            // own EU slab slot for next level's new split kk = s-1
            {
                int rrn = (s - 1) & 1;
                if (rr == rrn && lane < NNT) {
                    int tn = (s - 1 - rrn) >> 1;
                    sUV[uvt_base(w, lane, tn >> 3) + (tn & 7)] =
                        (short)f2bf(__expf(val - rm));
                }
            }
            // neighbor's epilogue -> fresh registers for next level (q<3)
            if (q < 3 && (i0 + 1) <= LL - s) {
                const float MqN = sM[q + 1];
                float sum2 = 0.f;
                #pragma unroll
                for (int w2 = 0; w2 < 8; ++w2) {
                    const float* pp = &pD[w2*PD_W + (ln >> 4)*PD_T + (ln & 15)];
                    sum2 += pp[(2*q + 2)*PD_RS] + pp[(2*q + 3)*PD_RS];
                }
                float valN = MqN + __logf(sum2);
                rmN = wavemax((lane < NNT) ? valN : -INFINITY);
                v0Reg = valN;
            }
        }
        // no B4: pD/sEb reuse is protected by next level's B2/B3
    }
}

extern "C" void kernel_launch(void* const* d_in, const int* in_sizes, int n_in,
                              void* d_out, int out_size, void* d_ws, size_t ws_size,
                              hipStream_t stream) {
    const int*   tokens  = (const int*)d_in[0];
    const float* binary  = (const float*)d_in[1];
    const float* lexical = (const float*)d_in[2];
    float* out = (float*)d_out;

    float* chart = (float*)d_ws;                                   // 6.49 MB
    unsigned short* Wp = (unsigned short*)(chart + (size_t)NCELL); // 221 KB bf16

    int T = in_sizes[2] / NNT;   // 32000

    int fill_blocks = (NCELL + 255)/256;                           // 6336
    prep_kernel<<<688 + fill_blocks, 256, 0, stream>>>(binary, tokens, lexical, Wp, chart, T);
    inside_kernel<<<256, 512, 0, stream>>>(Wp, chart, out);
}

// Round 19
// 118.233 us; speedup vs baseline: 1.0584x; 1.0425x over previous
//
#include <hip/hip_runtime.h>
#include <math.h>

#define NNT 48
#define LL 32
#define BB 32
#define N2 2304            // 48*48
#define KSTEPS 72          // 2304/32
#define EPSV 1e-30f
#define CH_J ((LL+1)*NNT)  // 1584
#define SEB_S 2328         // shorts per sEb row (2304 + pad)
#define PD_RS 20           // pD row stride (floats)
#define PD_T  328          // pD nt-tile stride (floats)
#define PD_W  984          // pD wave stride (floats)
#define NCELL (BB*LL*(LL+1)*NNT)   // 1,622,016 chart cells

typedef __attribute__((ext_vector_type(8))) short bf16x8;
typedef __attribute__((ext_vector_type(4))) float f32x4;
typedef __attribute__((ext_vector_type(4))) int   i32x4;

__device__ __forceinline__ int ch_idx(int b, int i, int j, int n) {
    return (((b*LL + i)*(LL+1) + j)*NNT + n);
}
__device__ __forceinline__ unsigned short f2bf(float x) {
    unsigned u = __float_as_uint(x);
    u = (u + 0x7fffu + ((u >> 16) & 1u)) >> 16;   // RNE
    return (unsigned short)u;
}
// packed f32x2 -> bf16x2 (RTZ) — one instruction (T12 primitive)
__device__ __forceinline__ int cvtpk(float lo, float hi) {
    int r;
    asm("v_cvt_pk_bf16_f32 %0, %1, %2" : "=v"(r) : "v"(lo), "v"(hi));
    return r;
}
// EU/EV slab addressing (shorts): [q][r=0..47][k=0..31] bf16, 16B-chunk XOR swizzle
__device__ __forceinline__ int uvt_base(int q, int r, int kc) {
    return q*1536 + ((((r << 2) + kc) ^ (r & 7)) << 3);
}
__device__ __forceinline__ float wavemax(float x) {
    #pragma unroll
    for (int o = 32; o; o >>= 1) x = fmaxf(x, __shfl_xor(x, o));
    return x;
}
// cross-XCD-safe (LLC-coherent) chart access — RELAXED, no inv/wb
__device__ __forceinline__ float ch_ld(const float* p) {
    return __hip_atomic_load(p, __ATOMIC_RELAXED, __HIP_MEMORY_SCOPE_AGENT);
}
__device__ __forceinline__ void ch_st(float* p, float v) {
    __hip_atomic_store(p, v, __ATOMIC_RELAXED, __HIP_MEMORY_SCOPE_AGENT);
}
// lgkm-only barrier: LDS ordering without draining in-flight chart stores
#define LBAR() { asm volatile("s_waitcnt lgkmcnt(0)" ::: "memory"); \
                 __builtin_amdgcn_s_barrier(); }

// prep: [0,432) pack W into MFMA B-frag order; [432,688) leaf rows + leaf rmax;
// [688,...) -inf sentinels into every non-leaf chart cell (data-as-flag).
__global__ void prep_kernel(const float* __restrict__ binary, const int* __restrict__ tokens,
                            const float* __restrict__ lexical, unsigned short* __restrict__ Wp,
                            float* __restrict__ chart, int T) {
    if (blockIdx.x < 432) {
        int idx = blockIdx.x*256 + threadIdx.x;       // 432*256 == 3*72*512
        int j  = idx & 7;
        int l  = (idx >> 3) & 63;
        int ks = (idx >> 9) % KSTEPS;
        int nt = idx / (KSTEPS*512);
        int e = ks*32 + ((l >> 4) << 3) + j;
        int n = nt*16 + (l & 15);
        int bp = e % 48, c = e / 48;
        Wp[idx] = f2bf(fmaxf(binary[n*N2 + bp*48 + c], EPSV));
    } else if (blockIdx.x < 688) {
        int row = (blockIdx.x - 432)*4 + (threadIdx.x >> 6);   // 1024 rows
        int lane = threadIdx.x & 63;
        int b = row >> 5, i = row & 31;
        int tok = tokens[b*LL + i];
        float val = (lane < NNT)
            ? __logf(fmaxf(lexical[(size_t)lane*(size_t)T + (size_t)tok], EPSV))
            : -INFINITY;
        float rm = wavemax(val);
        if (lane < NNT) chart[ch_idx(b, i, i+1, lane)] = val;
        if (lane == 0) chart[ch_idx(b, i, 0, i+1)] = rm;   // leaf rmax
    } else {
        int idx = (blockIdx.x - 688)*256 + threadIdx.x;
        if (idx < NCELL) {
            int n = idx % NNT;
            int r = idx / NNT;
            int j = r % (LL + 1);
            int i = (r / (LL + 1)) % LL;
            if (j != i + 1 && !(j == 0 && n == i + 1))
                chart[idx] = -INFINITY;
        }
    }
}

#define MFMA16(A,B,C) __builtin_amdgcn_mfma_f32_16x16x32_bf16(A,B,C,0,0,0)

// right-child row loads for split-slots [C*8, C*8+8) (kk = rr + t*2), clamped
#define LDVP(V, C, TCX, VPX)                                                   \
    { _Pragma("unroll")                                                        \
      for (int dt = 0; dt < 8; ++dt) {                                         \
          int t = (C)*8 + dt; int tt = (t < (TCX)) ? t : (TCX) - 1;            \
          int kk = rr + tt*2;                                                  \
          V[dt] = ch_ld((VPX) + kk*CH_J + ln);                                 \
      } }
// fresh-value override from LDS (instance q+1's previous-level output)
#define FRESHFIX(V)                                                            \
    { if (freshLDS) {                                                          \
          if (lane == 0) btP = sRm[q + 1][s - 1];                              \
          if (rr == 0) V[0] = sOut[q + 1][ln];                                 \
      } }
// consume EV chunk: two-sided shift (args <= 0), cvt_pk pack, b128 slab write
#define CONSCH(V, C)                                                           \
    { int pv[4];                                                               \
      _Pragma("unroll")                                                        \
      for (int dp = 0; dp < 4; ++dp) {                                         \
          int t0 = (C)*8 + 2*dp;                                               \
          int tt0 = (t0     < tc) ? t0     : tc - 1;                           \
          int tt1 = (t0 + 1 < tc) ? t0 + 1 : tc - 1;                           \
          float a0 = sRm[q][rr + tt0*2 + 1];                                   \
          float a1 = sRm[q][rr + tt1*2 + 1];                                   \
          float e0 = __expf(V[2*dp]     + a0 - M);                             \
          float e1 = __expf(V[2*dp + 1] + a1 - M);                             \
          pv[dp] = cvtpk(e0, e1);                                              \
      }                                                                        \
      if (lane < NNT) {                                                        \
          int ad = uvt_base(w, lane, (C));                                     \
          *(i32x4*)&sUV[ad + 12288] = (i32x4){pv[0],pv[1],pv[2],pv[3]};        \
      } }

// 256 blocks, 512 thr. Gang of 8 blocks per b at blockIdx = b + 32c (same XCD).
// Block c owns i = 28-4c..31-4c; 2 waves per instance (split parity).
// Level-invariant: Wp in 108 VGPRs (stage-2 VMEM-free); EU slabs persistent,
// ONE new slot/level. v-row/beta loads software-pipelined ONE LEVEL AHEAD.
// kk>=1 slots are provably final at prefetch-issue time; the kk=0 slot is
// fresh: q<3 takes it from LDS (FRESHFIX), q=3 RE-LOADS just that value at
// consumption time.
__global__ __launch_bounds__(512, 2) void inside_kernel(
        const unsigned short* __restrict__ Wp,
        float* __restrict__ chart,
        float* __restrict__ out) {
    const int pb = blockIdx.x;
    const int b = pb & 31, c = pb >> 5;
    const int i_base = 28 - 4*c;
    const int tid = threadIdx.x, lane = tid & 63, w = tid >> 6;
    const int fr = lane & 15, kg = lane >> 4;
    const int ln = (lane < NNT) ? lane : 0;
    const int q = w >> 1, rr = w & 1;       // instance slot, split parity
    const int i0 = i_base + q;

    __shared__ __align__(16) short sUV[24576];       // EU(persist) | EV(+12288)
    __shared__ __align__(16) short sEb[16*SEB_S];    //                 74.5 KB
    __shared__ float pD[8*PD_W];                     //                 31.5 KB
    __shared__ float sRm[4][33];                     // own-row maxima cache
    __shared__ float sOut[4][NNT];                   // own prev-level outputs

    for (int x = tid; x < 12288; x += 512) ((int*)sUV)[x] = 0;
    for (int x = tid; x < 18624; x += 512) ((int*)sEb)[x] = 0;
    if (tid < 4)   // own leaf rmax -> cache
        sRm[tid][1] = ch_ld(&chart[ch_idx(b, i_base + tid, 0, i_base + tid + 1)]);
    if (w < 4 && lane < NNT)   // own leaf row -> sOut (seeds EU slot 0 at s=2)
        sOut[w][lane] = ch_ld(&chart[ch_idx(b, i_base + w, i_base + w + 1, lane)]);

    // level-invariant Wp B-fragments -> 108 VGPRs (stage-2 becomes VMEM-free)
    const bf16x8* wp8 = (const bf16x8*)Wp;
    const int kstart = 9*w;
    bf16x8 wreg[9][3];
    #pragma unroll
    for (int t = 0; t < 9; ++t)
        #pragma unroll
        for (int nt = 0; nt < 3; ++nt)
            wreg[t][nt] = wp8[(nt*KSTEPS + kstart + t)*64 + lane];

    // ---- cross-level prefetch registers + prologue (level 2: all leaves)
    float vvP0[8] = {0,0,0,0,0,0,0,0}, vvP1[8] = {0,0,0,0,0,0,0,0}, btP = 0.f;
    if (i0 <= LL - 2) {
        const int nkn = 1, tcn = (nkn - rr + 1) >> 1;
        if (tcn > 0) {
            const float* vpn = chart + ch_idx(b, i0 + 1, i0 + 2, 0);
            const float* bpn = chart + ch_idx(b, i0 + 1, 0, i0 + 2);
            btP = (lane < nkn) ? ch_ld(bpn + lane*CH_J) : 0.f;
            LDVP(vvP0, 0, tcn, vpn)
        }
    }

    __syncthreads();

    for (int s = 2; s <= LL; ++s) {
        const int nk = s - 1;
        if (i_base > LL - s) return;                       // block done forever

        const bool active = (i0 <= LL - s);
        const int tc = active ? ((nk - rr + 1) >> 1) : 0;  // owned splits (parity rr)
        const bool freshLDS = active && (s > 2) && (q < 3);
        float M = -INFINITY;
        f32x4 ea[9];
        #pragma unroll
        for (int z = 0; z < 9; ++z) ea[z] = (f32x4){0.f, 0.f, 0.f, 0.f};

        // incremental EU: the level's NEW split kk = nk-1 belongs to wave
        // parity (nk-1)&1; its u row = instance q's level-(s-1) output (sOut).
        if (active && rr == ((nk - 1) & 1) && lane < NNT) {
            int tn = (nk - 1 - rr) >> 1;
            float eu = __expf(sOut[q][lane] - sRm[q][s - 1]);
            sUV[uvt_base(w, lane, tn >> 3) + (tn & 7)] = (short)f2bf(eu);
        }

        if (tc > 0) {
            const float* vp = chart + ch_idx(b, i0 + 1, i0 + s, 0);
            const float* bp = chart + ch_idx(b, i0 + 1, 0, i0 + s);  // beta col

            // consume prefetched values; patch the fresh kk=0 slot:
            //  q<3: from LDS; q=3: targeted consumption-time reload (cross-block)
            FRESHFIX(vvP0)
            if (q == 3 && s > 2) {
                if (lane == 0) btP = ch_ld(bp);
                if (rr == 0)  vvP0[0] = ch_ld(vp + ln);
            }
            for (;;) {   // safety net (covers in-flight-store races; rare)
                bool bad = (lane < nk) && (btP == -INFINITY);
                #pragma unroll
                for (int dt = 0; dt < 8; ++dt) bad |= (vvP0[dt] == -INFINITY);
                if (tc > 8) {
                    #pragma unroll
                    for (int dt = 0; dt < 8; ++dt) bad |= (vvP1[dt] == -INFINITY);
                }
                if (!__any(bad)) break;
                btP = (lane < nk) ? ch_ld(bp + lane*CH_J) : 0.f;
                LDVP(vvP0, 0, tc, vp)
                if (tc > 8) { LDVP(vvP1, 1, tc, vp) }
                FRESHFIX(vvP0)
            }

            // M = max_k (alpha_k + beta_k); alpha from LDS cache
            {
                float al = (lane < nk) ? sRm[q][lane + 1] : -INFINITY;
                M = wavemax((lane < nk) ? al + btP : -INFINITY);
            }

            CONSCH(vvP0, 0)
            if (tc > 8) { CONSCH(vvP1, 1) }

            // stage-1 MFMA: E[b'][c] partial = sum_t EU[t][b'] * EV[t][c]
            bf16x8 A0 = *(const bf16x8*)&sUV[uvt_base(w,  0 + fr, kg)];
            bf16x8 A1 = *(const bf16x8*)&sUV[uvt_base(w, 16 + fr, kg)];
            bf16x8 A2 = *(const bf16x8*)&sUV[uvt_base(w, 32 + fr, kg)];
            bf16x8 B0 = *(const bf16x8*)&sUV[12288 + uvt_base(w,  0 + fr, kg)];
            bf16x8 B1 = *(const bf16x8*)&sUV[12288 + uvt_base(w, 16 + fr, kg)];
            bf16x8 B2 = *(const bf16x8*)&sUV[12288 + uvt_base(w, 32 + fr, kg)];
            ea[0] = MFMA16(A0,B0,ea[0]); ea[1] = MFMA16(A0,B1,ea[1]); ea[2] = MFMA16(A0,B2,ea[2]);
            ea[3] = MFMA16(A1,B0,ea[3]); ea[4] = MFMA16(A1,B1,ea[4]); ea[5] = MFMA16(A1,B2,ea[5]);
            ea[6] = MFMA16(A2,B0,ea[6]); ea[7] = MFMA16(A2,B1,ea[7]); ea[8] = MFMA16(A2,B2,ea[8]);
        }

        // issue NEXT level's v/beta prefetch (kk>=1 slots provably final;
        // kk=0 slot handled by LDS/targeted-reload next level)
        if (s < LL && i0 <= LL - s - 1) {
            const int nkn = s;
            const int tcn = (nkn - rr + 1) >> 1;
            const float* vpn = chart + ch_idx(b, i0 + 1, i0 + s + 1, 0);
            const float* bpn = chart + ch_idx(b, i0 + 1, 0, i0 + s + 1);
            btP = (lane < nkn) ? ch_ld(bpn + lane*CH_J) : 0.f;
            LDVP(vvP0, 0, tcn, vpn)
            if (tcn > 8) { LDVP(vvP1, 1, tcn, vpn) }
        }

        // pack partial E -> sEb row w (cvt_pk, RTZ)
        if (active) {
            #pragma unroll
            for (int mt = 0; mt < 3; ++mt) {
                #pragma unroll
                for (int ct = 0; ct < 3; ++ct) {
                    f32x4 d = ea[mt*3 + ct];
                    int e0 = (ct*16 + fr)*48 + mt*16 + kg*4;
                    unsigned lo = (unsigned)cvtpk(d[0], d[1]);
                    unsigned hi = (unsigned)cvtpk(d[2], d[3]);
                    *(unsigned long long*)&sEb[w*SEB_S + e0] =
                        (unsigned long long)lo | ((unsigned long long)hi << 32);
                }
            }
        }

        LBAR();   // B2: sEb visible (chart stores stay in flight)

        // stage-2: K-split MFMA GEMM [16 x 2304] x [2304 x 48] — VMEM-free
        {
            f32x4 c0 = {0.f,0.f,0.f,0.f}, c1 = c0, c2 = c0;
            #pragma unroll
            for (int t = 0; t < 9; ++t) {
                bf16x8 af = *(const bf16x8*)&sEb[fr*SEB_S + (kstart + t)*32 + kg*8];
                c0 = MFMA16(af, wreg[t][0], c0);
                c1 = MFMA16(af, wreg[t][1], c1);
                c2 = MFMA16(af, wreg[t][2], c2);
            }
            #pragma unroll
            for (int r2 = 0; r2 < 4; ++r2) {
                int row = kg*4 + r2;
                pD[w*PD_W + 0*PD_T + row*PD_RS + fr] = c0[r2];
                pD[w*PD_W + 1*PD_T + row*PD_RS + fr] = c1[r2];
                pD[w*PD_W + 2*PD_T + row*PD_RS + fr] = c2[r2];
            }
        }
        LBAR();   // B3: pD visible

        // epilogue: wave rr==0 of instance q -> publish row (chart + LDS)
        if (active && rr == 0) {
            float sum = 0.f;
            #pragma unroll
            for (int w2 = 0; w2 < 8; ++w2) {
                const float* pp = &pD[w2*PD_W + (ln >> 4)*PD_T + (ln & 15)];
                sum += pp[(2*q)*PD_RS] + pp[(2*q + 1)*PD_RS];
            }
            float val = M + __logf(sum);
            float rm = wavemax((lane < NNT) ? val : -INFINITY);
            if (lane < NNT) {
                ch_st(&chart[ch_idx(b, i0, i0 + s, lane)], val);
                sOut[q][lane] = val;
            }
            if (lane == 0) {
                ch_st(&chart[ch_idx(b, i0, 0, i0 + s)], rm);
                sRm[q][s] = rm;
                if (s == LL) out[b] = val;
            }
        }
        LBAR();   // B4: sOut/sRm visible; LDS reuse safe
    }
}

extern "C" void kernel_launch(void* const* d_in, const int* in_sizes, int n_in,
                              void* d_out, int out_size, void* d_ws, size_t ws_size,
                              hipStream_t stream) {
    const int*   tokens  = (const int*)d_in[0];
    const float* binary  = (const float*)d_in[1];
    const float* lexical = (const float*)d_in[2];
    float* out = (float*)d_out;

    float* chart = (float*)d_ws;                                   // 6.49 MB
    unsigned short* Wp = (unsigned short*)(chart + (size_t)NCELL); // 221 KB bf16

    int T = in_sizes[2] / NNT;   // 32000

    int fill_blocks = (NCELL + 255)/256;                           // 6336
    prep_kernel<<<688 + fill_blocks, 256, 0, stream>>>(binary, tokens, lexical, Wp, chart, T);
    inside_kernel<<<256, 512, 0, stream>>>(Wp, chart, out);
}